// Round 16
// baseline (294.883 us; speedup 1.0000x reference)
//
#include <hip/hip_runtime.h>

#define N_NODES 50000
#define IN_DIM 512
#define HIDDEN 64
#define OUT_DIM 47
#define HSTRIDE 448  // hcat row stride (bf16): [h0(64) | hA(128) | hB(256)]

#define NBINS 391    // ceil(50000/128); bin = dst >> 7
#define CAP1 3072
#define CAP2 4096
#define CHUNK 2048   // edges per binning block (16 KB LDS sort buffer)

typedef unsigned short u16;
typedef short v8s __attribute__((ext_vector_type(8)));
typedef float v4f __attribute__((ext_vector_type(4)));

union F4 { float4 v; float f[4]; };
union U4 { uint4 v; unsigned u[4]; };

static __device__ __forceinline__ u16 f2bf(float f) {
  unsigned u = __float_as_uint(f);
  u += 0x7fffu + ((u >> 16) & 1u);
  return (u16)(u >> 16);
}
static __device__ __forceinline__ float bf2f(u16 h) {
  return __uint_as_float(((unsigned)h) << 16);
}

// ---------------------------------------------------------------------------
// prep (fused, r9-proven pattern): [0,16) conv embed_w; [16,27) conv cls_w;
// [27, 27+c1+c2) bin_edges LDS chunk-sort (r15-proven) -> staging bursts.
// ---------------------------------------------------------------------------
__global__ __launch_bounds__(256) void prep(
    const float* __restrict__ embed_w, u16* __restrict__ weTh,
    u16* __restrict__ weTl, const float* __restrict__ cls_w,
    u16* __restrict__ wcTh, u16* __restrict__ wcTl,
    const int* __restrict__ src1, const int* __restrict__ dst1,
    const float* __restrict__ w1, int E1, int c1,
    const int* __restrict__ src2, const int* __restrict__ dst2,
    const float* __restrict__ w2, int E2,
    int* __restrict__ binCursor, int2* __restrict__ stg1,
    int2* __restrict__ stg2) {
  __shared__ int hist[NBINS], sbase[NBINS], cur[NBINS], segrel[NBINS];
  __shared__ int wsum[4];
  __shared__ int2 buf[CHUNK];

  int b = blockIdx.x;
  if (b < 16) {
    int tid = b * 256 + threadIdx.x;  // 64 cols * 64 kgroups
    int col = tid >> 6;
    int k8 = (tid & 63) * 8;
#pragma unroll
    for (int j = 0; j < 8; j++) {
      float v = embed_w[(size_t)(k8 + j) * HIDDEN + col];
      u16 h = f2bf(v);
      weTh[(size_t)col * IN_DIM + k8 + j] = h;
      weTl[(size_t)col * IN_DIM + k8 + j] = f2bf(v - bf2f(h));
    }
    return;
  }
  if (b < 27) {
    int tid = (b - 16) * 256 + threadIdx.x;  // 48 cols * 56 kgroups
    if (tid < 48 * 56) {
      int col = tid / 56;
      int k8 = (tid % 56) * 8;
#pragma unroll
      for (int j = 0; j < 8; j++) {
        float v = (col < OUT_DIM) ? cls_w[(size_t)(k8 + j) * OUT_DIM + col] : 0.f;
        u16 h = f2bf(v);
        wcTh[(size_t)col * HSTRIDE + k8 + j] = h;
        wcTl[(size_t)col * HSTRIDE + k8 + j] = f2bf(v - bf2f(h));
      }
    }
    return;
  }

  int q = b - 27;
  const int *src, *dst;
  const float* w;
  int E, cap;
  int2* stg;
  int* bc;
  if (q < c1) {
    src = src1; dst = dst1; w = w1; E = E1; stg = stg1; bc = binCursor; cap = CAP1;
  } else {
    q -= c1;
    src = src2; dst = dst2; w = w2; E = E2; stg = stg2; bc = binCursor + NBINS; cap = CAP2;
  }
  int e0 = q * CHUNK;
  int n = E - e0;
  if (n > CHUNK) n = CHUNK;
  int t = threadIdx.x;

  for (int i = t; i < NBINS; i += 256) hist[i] = 0;
  __syncthreads();

  // load 8 edges/thread into registers + LDS histogram
  int2 pk[8];
#pragma unroll
  for (int j = 0; j < 8; j++) {
    int idx = t + j * 256;
    if (idx < n) {
      int d = dst[e0 + idx];
      int bin = d >> 7;
      pk[j] = make_int2(src[e0 + idx] | ((d & 127) << 16) | (bin << 23),
                        __float_as_int(w[e0 + idx]));
      atomicAdd(&hist[bin], 1);
    } else {
      pk[j].x = -1;
    }
  }
  __syncthreads();

  // exclusive scan hist -> sbase (thread t owns bins 2t, 2t+1; 196 active)
  int a0 = 0, a1 = 0;
  if (t < 196) {
    a0 = hist[2 * t];
    if (2 * t + 1 < NBINS) a1 = hist[2 * t + 1];
  }
  int s = a0 + a1;
  int lane = t & 63, wid = t >> 6;
  int ps = s;
#pragma unroll
  for (int off = 1; off < 64; off <<= 1) {
    int v = __shfl_up(ps, off, 64);
    if (lane >= off) ps += v;
  }
  if (lane == 63) wsum[wid] = ps;
  __syncthreads();
  if (t == 0) {
    int c = 0;
#pragma unroll
    for (int i = 0; i < 4; i++) { int tmp = wsum[i]; wsum[i] = c; c += tmp; }
  }
  __syncthreads();
  int excl = ps - s + wsum[wid];
  if (t < 196) {
    sbase[2 * t] = excl;
    cur[2 * t] = excl;
    if (2 * t + 1 < NBINS) { sbase[2 * t + 1] = excl + a0; cur[2 * t + 1] = excl + a0; }
  }
  __syncthreads();

  // reorder into bin-sorted LDS buffer
#pragma unroll
  for (int j = 0; j < 8; j++) {
    if (pk[j].x != -1) {
      int bin = (pk[j].x >> 23) & 0x1FF;
      int pos = atomicAdd(&cur[bin], 1);
      buf[pos] = pk[j];
    }
  }
  for (int i = t; i < NBINS; i += 256) {
    int h = hist[i];
    segrel[i] = h ? atomicAdd(&bc[i], h) : 0;
  }
  __syncthreads();

  // burst-write bin runs contiguously to staging
  for (int i = t; i < n; i += 256) {
    int2 e = buf[i];
    int bin = (e.x >> 23) & 0x1FF;
    int pos = segrel[bin] + (i - sbase[bin]);
    if (pos < cap)
      stg[(size_t)bin * cap + pos] = make_int2(e.x & 0x7FFFFF, e.y);
  }
}

// ---------------------------------------------------------------------------
// embed_mfma (restructured r16): grid = 3125 blocks x 4 waves.
// Block = 16 rows x 64 cols; wave = one 16x16 col-fragment (nf=1).
// All 4 waves load the SAME x fragments (L1-served); w L2-hot.
// acc = 4 VGPRs -> occupancy cap is the 32-wave/CU HW limit.
// A: fp32 x -> single bf16 convert; B hi/lo split (2 MFMA/step).
// C/D: col=lane&15, row=(lane>>4)*4+reg  [m89-verified]
// ---------------------------------------------------------------------------
__global__ __launch_bounds__(256) void embed_mfma(
    const float* __restrict__ x, const u16* __restrict__ wTh,
    const u16* __restrict__ wTl, const float* __restrict__ bias,
    u16* __restrict__ hcat) {
  int wave = threadIdx.x >> 6, lane = threadIdx.x & 63;
  int row0 = blockIdx.x * 16;
  int m = lane & 15, kq = lane >> 4;
  int rowA = row0 + m;
  if (rowA >= N_NODES) rowA = N_NODES - 1;
  const float* xr = x + (size_t)rowA * IN_DIM;
  int col = wave * 16 + m;
  const u16* bhp = wTh + (size_t)col * IN_DIM;
  const u16* blp = wTl + (size_t)col * IN_DIM;

  v4f acc = (v4f){0.f, 0.f, 0.f, 0.f};

#pragma unroll 8
  for (int k0 = 0; k0 < IN_DIM; k0 += 32) {
    int kk = k0 + kq * 8;
    F4 p, qv;
    p.v = *(const float4*)(xr + kk);
    qv.v = *(const float4*)(xr + kk + 4);
    v8s a;
#pragma unroll
    for (int j = 0; j < 4; j++) {
      a[j] = (short)f2bf(p.f[j]);
      a[4 + j] = (short)f2bf(qv.f[j]);
    }
    v8s bh = *(const v8s*)(bhp + kk);
    v8s bl = *(const v8s*)(blp + kk);
    acc = __builtin_amdgcn_mfma_f32_16x16x32_bf16(a, bh, acc, 0, 0, 0);
    acc = __builtin_amdgcn_mfma_f32_16x16x32_bf16(a, bl, acc, 0, 0, 0);
  }

  float bv = bias[col];
#pragma unroll
  for (int reg = 0; reg < 4; reg++) {
    int rowC = row0 + kq * 4 + reg;
    if (rowC < N_NODES) {
      float v = acc[reg] + bv;
      hcat[(size_t)rowC * HSTRIDE + col] = f2bf(v > 0.f ? v : 0.f);
    }
  }
}

// ---------------------------------------------------------------------------
// binscan: exclusive scan of the NBINS bin counts per list (grid=2).
// ---------------------------------------------------------------------------
__global__ __launch_bounds__(512) void binscan(const int* __restrict__ cnt,
                                               int* __restrict__ scanout) {
  const int* in = cnt + blockIdx.x * NBINS;
  int* out = scanout + blockIdx.x * NBINS;
  int tid = threadIdx.x, lane = tid & 63, wid = tid >> 6;
  __shared__ int wsum[8];
  int v0 = (tid < NBINS) ? in[tid] : 0;
  int v = v0;
#pragma unroll
  for (int off = 1; off < 64; off <<= 1) {
    int t = __shfl_up(v, off, 64);
    if (lane >= off) v += t;
  }
  if (lane == 63) wsum[wid] = v;
  __syncthreads();
  if (tid < 8) {
    int s = wsum[tid], sc = s;
#pragma unroll
    for (int off = 1; off < 8; off <<= 1) {
      int t = __shfl_up(sc, off, 8);
      if (tid >= off) sc += t;
    }
    wsum[tid] = sc - s;
  }
  __syncthreads();
  if (tid < NBINS) out[tid] = v - v0 + wsum[wid];
}

// ---------------------------------------------------------------------------
// place (standalone): one block per (list,bin) — per-bin CSR placement.
// ---------------------------------------------------------------------------
__global__ __launch_bounds__(256) void place(
    const int* __restrict__ binCursor, const int* __restrict__ binScan,
    const int2* __restrict__ stg1, int2* __restrict__ ew1,
    int* __restrict__ ep1, const int2* __restrict__ stg2,
    int2* __restrict__ ew2, int* __restrict__ ep2) {
  int pb = blockIdx.x;
  int lb = pb < NBINS ? pb : pb - NBINS;
  const int2* stg;
  int2* ew;
  int* ep;
  int cap;
  if (pb < NBINS) { stg = stg1; ew = ew1; ep = ep1; cap = CAP1; }
  else            { stg = stg2; ew = ew2; ep = ep2; cap = CAP2; }
  int cnt = binCursor[pb];
  if (cnt > cap) cnt = cap;
  int base = binScan[pb];
  const int2* seg = stg + (size_t)lb * cap;
  int node0 = lb << 7;
  int nnodes = N_NODES - node0;
  if (nnodes > 128) nnodes = 128;

  __shared__ int ncnt[128], noff[128], ncur[128];
  __shared__ int t0;
  if (threadIdx.x < 128) { ncnt[threadIdx.x] = 0; ncur[threadIdx.x] = 0; }
  __syncthreads();
  for (int t = threadIdx.x; t < cnt; t += 256)
    atomicAdd(&ncnt[(seg[t].x >> 16) & 127], 1);
  __syncthreads();
  int v0 = 0, v = 0;
  if (threadIdx.x < 128) {
    v0 = ncnt[threadIdx.x];
    v = v0;
    int lane = threadIdx.x & 63;
#pragma unroll
    for (int off = 1; off < 64; off <<= 1) {
      int t = __shfl_up(v, off, 64);
      if (lane >= off) v += t;
    }
    if (threadIdx.x == 63) t0 = v;
  }
  __syncthreads();
  if (threadIdx.x < 128) {
    int excl = v - v0 + (threadIdx.x >= 64 ? t0 : 0);
    noff[threadIdx.x] = excl;
    if (threadIdx.x < nnodes) ep[node0 + threadIdx.x] = base + excl + v0;
  }
  __syncthreads();
  for (int t = threadIdx.x; t < cnt; t += 256) {
    int2 pk = seg[t];
    int nl = (pk.x >> 16) & 127;
    int pos = base + noff[nl] + atomicAdd(&ncur[nl], 1);
    ew[pos] = make_int2(pk.x & 0xFFFF, pk.y);
  }
}

// ---------------------------------------------------------------------------
// gather2 (fused pair): blocks [0,half) = list1 -> out1, rest = list2 -> out2.
// ---------------------------------------------------------------------------
__device__ __forceinline__ void bf8_fma(const U4& r, float wt, float* a) {
#pragma unroll
  for (int i = 0; i < 4; i++) {
    a[2 * i]     += wt * __uint_as_float(r.u[i] << 16);
    a[2 * i + 1] += wt * __uint_as_float(r.u[i] & 0xffff0000u);
  }
}

template <int NT>
__global__ __launch_bounds__(256) void gather2(
    const int* __restrict__ ep1, const int2* __restrict__ ew1,
    const int* __restrict__ ep2, const int2* __restrict__ ew2,
    const u16* __restrict__ hin, u16* __restrict__ out1,
    u16* __restrict__ out2, int half_blocks) {
  int b = blockIdx.x;
  const int* ep;
  const int2* ew;
  u16* out;
  if (b < half_blocks) { ep = ep1; ew = ew1; out = out1; }
  else { b -= half_blocks; ep = ep2; ew = ew2; out = out2; }

  int tid = b * 256 + threadIdx.x;
  int node = tid / NT;
  if (node >= N_NODES) return;
  int col0 = (tid % NT) * 8;
  int s = node ? ep[node - 1] : 0;
  int e = ep[node];

  float a0[8], a1[8];
#pragma unroll
  for (int i = 0; i < 8; i++) { a0[i] = 0.f; a1[i] = 0.f; }

  int j = s;
  for (; j + 4 <= e; j += 4) {
    int2 p0 = ew[j], p1 = ew[j + 1], p2 = ew[j + 2], p3 = ew[j + 3];
    U4 r0, r1, r2, r3;
    r0.v = *(const uint4*)(hin + (size_t)p0.x * HSTRIDE + col0);
    r1.v = *(const uint4*)(hin + (size_t)p1.x * HSTRIDE + col0);
    r2.v = *(const uint4*)(hin + (size_t)p2.x * HSTRIDE + col0);
    r3.v = *(const uint4*)(hin + (size_t)p3.x * HSTRIDE + col0);
    bf8_fma(r0, __int_as_float(p0.y), a0);
    bf8_fma(r1, __int_as_float(p1.y), a1);
    bf8_fma(r2, __int_as_float(p2.y), a0);
    bf8_fma(r3, __int_as_float(p3.y), a1);
  }
  for (; j < e; j++) {
    int2 p = ew[j];
    U4 r;
    r.v = *(const uint4*)(hin + (size_t)p.x * HSTRIDE + col0);
    bf8_fma(r, __int_as_float(p.y), a0);
  }

  U4 o;
#pragma unroll
  for (int i = 0; i < 4; i++) {
    float lo = a0[2 * i] + a1[2 * i];
    float hi = a0[2 * i + 1] + a1[2 * i + 1];
    lo = lo > 0.f ? lo : 0.f;
    hi = hi > 0.f ? hi : 0.f;
    o.u[i] = ((unsigned)f2bf(hi) << 16) | (unsigned)f2bf(lo);
  }
  *(uint4*)(out + (size_t)node * HSTRIDE + col0) = o.v;
}

// ---------------------------------------------------------------------------
// final: out = hcat(bf16) @ cls_w + b. A direct bf16, B split hi/lo (2 MFMA).
// ---------------------------------------------------------------------------
__global__ __launch_bounds__(256) void final_mfma(
    const u16* __restrict__ hcat, const u16* __restrict__ wTh,
    const u16* __restrict__ wTl, const float* __restrict__ bias,
    float* __restrict__ out) {
  int wave = threadIdx.x >> 6, lane = threadIdx.x & 63;
  int row0 = blockIdx.x * 64 + wave * 16;
  int m = lane & 15, kq = lane >> 4;
  int rowA = row0 + m;
  if (rowA >= N_NODES) rowA = N_NODES - 1;
  const u16* hr = hcat + (size_t)rowA * HSTRIDE;

  v4f acc[3];
#pragma unroll
  for (int nf = 0; nf < 3; nf++) acc[nf] = (v4f){0.f, 0.f, 0.f, 0.f};

#pragma unroll 2
  for (int k0 = 0; k0 < HSTRIDE; k0 += 32) {
    int kk = k0 + kq * 8;
    v8s a = *(const v8s*)(hr + kk);
#pragma unroll
    for (int nf = 0; nf < 3; nf++) {
      int col = nf * 16 + m;
      v8s bh = *(const v8s*)(wTh + (size_t)col * HSTRIDE + kk);
      v8s bl = *(const v8s*)(wTl + (size_t)col * HSTRIDE + kk);
      acc[nf] = __builtin_amdgcn_mfma_f32_16x16x32_bf16(a, bh, acc[nf], 0, 0, 0);
      acc[nf] = __builtin_amdgcn_mfma_f32_16x16x32_bf16(a, bl, acc[nf], 0, 0, 0);
    }
  }

#pragma unroll
  for (int nf = 0; nf < 3; nf++) {
    int col = nf * 16 + m;
    if (col < OUT_DIM) {
      float bv = bias[col];
#pragma unroll
      for (int reg = 0; reg < 4; reg++) {
        int rowC = row0 + kq * 4 + reg;
        if (rowC < N_NODES)
          out[(size_t)rowC * OUT_DIM + col] = acc[nf][reg] + bv;
      }
    }
  }
}

// ---------------------------------------------------------------------------
extern "C" void kernel_launch(void* const* d_in, const int* in_sizes, int n_in,
                              void* d_out, int out_size, void* d_ws,
                              size_t ws_size, hipStream_t stream) {
  const float* x       = (const float*)d_in[0];
  const int*   src1    = (const int*)d_in[1];
  const int*   dst1    = (const int*)d_in[2];
  const float* w1      = (const float*)d_in[3];
  const int*   src2    = (const int*)d_in[4];
  const int*   dst2    = (const int*)d_in[5];
  const float* w2      = (const float*)d_in[6];
  const float* embed_w = (const float*)d_in[7];
  const float* embed_b = (const float*)d_in[8];
  const float* cls_w   = (const float*)d_in[9];
  const float* cls_b   = (const float*)d_in[10];
  int E1 = in_sizes[1];
  int E2 = in_sizes[4];

  float* ws = (float*)d_ws;
  size_t off = 0;
  u16* hcat = (u16*)(ws + off); off += (size_t)N_NODES * HSTRIDE / 2;
  int2* ew1 = (int2*)(ws + off); off += (size_t)2 * E1;
  int2* ew2 = (int2*)(ws + off); off += (size_t)2 * E2;
  int* ep1 = (int*)(ws + off); off += N_NODES;
  int* ep2 = (int*)(ws + off); off += N_NODES;
  int2* stg1 = (int2*)(ws + off); off += (size_t)2 * NBINS * CAP1;
  int2* stg2 = (int2*)(ws + off); off += (size_t)2 * NBINS * CAP2;
  int* binCursor = (int*)(ws + off); off += 2 * NBINS;
  int* binScan = (int*)(ws + off); off += 2 * NBINS;
  u16* weTh = (u16*)(ws + off); off += 16384;
  u16* weTl = (u16*)(ws + off); off += 16384;
  u16* wcTh = (u16*)(ws + off); off += 10752;
  u16* wcTl = (u16*)(ws + off); off += 10752;

  int c1 = (E1 + CHUNK - 1) / CHUNK;
  int c2 = (E2 + CHUNK - 1) / CHUNK;

  hipMemsetAsync(binCursor, 0, 2 * NBINS * sizeof(int), stream);
  prep<<<27 + c1 + c2, 256, 0, stream>>>(
      embed_w, weTh, weTl, cls_w, wcTh, wcTl,
      src1, dst1, w1, E1, c1, src2, dst2, w2, E2,
      binCursor, stg1, stg2);
  embed_mfma<<<3125, 256, 0, stream>>>(x, weTh, weTl, embed_b, hcat);
  binscan<<<2, 512, 0, stream>>>(binCursor, binScan);
  place<<<2 * NBINS, 256, 0, stream>>>(binCursor, binScan,
                                       stg1, ew1, ep1, stg2, ew2, ep2);
  // k=1: cols 64:128 <- A1 @ hcat[:,0:64]; cols 128:192 <- A2 @ same
  gather2<8><<<3126, 256, 0, stream>>>(ep1, ew1, ep2, ew2, hcat,
                                       hcat + 64, hcat + 128, 1563);
  // k=2: cols 192:320 <- A1 @ hcat[:,64:192]; cols 320:448 <- A2 @ same
  gather2<16><<<6250, 256, 0, stream>>>(ep1, ew1, ep2, ew2, hcat + 64,
                                        hcat + 192, hcat + 320, 3125);
  final_mfma<<<782, 256, 0, stream>>>(hcat, wcTh, wcTl, cls_b, (float*)d_out);
}

// Round 17
// 271.518 us; speedup vs baseline: 1.0861x; 1.0861x over previous
//
#include <hip/hip_runtime.h>

#define N_NODES 50000
#define IN_DIM 512
#define HIDDEN 64
#define OUT_DIM 47
#define HSTRIDE 448  // hcat row stride (bf16): [h0(64) | hA(128) | hB(256)]

#define NBINS 391    // ceil(50000/128); bin = dst >> 7
#define CAP1 3072
#define CAP2 4096
#define CHUNK 2048   // edges per binning block (16 KB LDS sort buffer)
#define XB 1024      // x-conversion blocks

typedef unsigned short u16;
typedef short v8s __attribute__((ext_vector_type(8)));
typedef float v4f __attribute__((ext_vector_type(4)));

union F4 { float4 v; float f[4]; };
union U4 { uint4 v; unsigned u[4]; };

static __device__ __forceinline__ u16 f2bf(float f) {
  unsigned u = __float_as_uint(f);
  u += 0x7fffu + ((u >> 16) & 1u);
  return (u16)(u >> 16);
}
static __device__ __forceinline__ float bf2f(u16 h) {
  return __uint_as_float(((unsigned)h) << 16);
}

// ---------------------------------------------------------------------------
// prep (fused): [0,16) conv embed_w; [16,27) conv cls_w; [27,27+XB) x->bf16;
// [27+XB, ...) bin_edges LDS chunk-sort (r15-proven, burst staging writes).
// ---------------------------------------------------------------------------
__global__ __launch_bounds__(256) void prep(
    const float* __restrict__ embed_w, u16* __restrict__ weTh,
    u16* __restrict__ weTl, const float* __restrict__ cls_w,
    u16* __restrict__ wcTh, u16* __restrict__ wcTl,
    const float* __restrict__ x, u16* __restrict__ x_bf,
    const int* __restrict__ src1, const int* __restrict__ dst1,
    const float* __restrict__ w1, int E1, int c1,
    const int* __restrict__ src2, const int* __restrict__ dst2,
    const float* __restrict__ w2, int E2,
    int* __restrict__ binCursor, int2* __restrict__ stg1,
    int2* __restrict__ stg2) {
  __shared__ int hist[NBINS], sbase[NBINS], cur[NBINS], segrel[NBINS];
  __shared__ int wsum[4];
  __shared__ int2 buf[CHUNK];

  int b = blockIdx.x;
  if (b < 16) {
    int tid = b * 256 + threadIdx.x;  // 64 cols * 64 kgroups
    int col = tid >> 6;
    int k8 = (tid & 63) * 8;
#pragma unroll
    for (int j = 0; j < 8; j++) {
      float v = embed_w[(size_t)(k8 + j) * HIDDEN + col];
      u16 h = f2bf(v);
      weTh[(size_t)col * IN_DIM + k8 + j] = h;
      weTl[(size_t)col * IN_DIM + k8 + j] = f2bf(v - bf2f(h));
    }
    return;
  }
  if (b < 27) {
    int tid = (b - 16) * 256 + threadIdx.x;  // 48 cols * 56 kgroups
    if (tid < 48 * 56) {
      int col = tid / 56;
      int k8 = (tid % 56) * 8;
#pragma unroll
      for (int j = 0; j < 8; j++) {
        float v = (col < OUT_DIM) ? cls_w[(size_t)(k8 + j) * OUT_DIM + col] : 0.f;
        u16 h = f2bf(v);
        wcTh[(size_t)col * HSTRIDE + k8 + j] = h;
        wcTl[(size_t)col * HSTRIDE + k8 + j] = f2bf(v - bf2f(h));
      }
    }
    return;
  }
  if (b < 27 + XB) {
    // x (fp32) -> x_bf (bf16), grid-stride over float4s
    const float4* x4 = (const float4*)x;
    uint2* o2 = (uint2*)x_bf;
    int i0 = (b - 27) * 256 + threadIdx.x;
    int stride = XB * 256;
    int tot = N_NODES * IN_DIM / 4;
    for (int i = i0; i < tot; i += stride) {
      F4 v;
      v.v = x4[i];
      uint2 o;
      o.x = (unsigned)f2bf(v.f[0]) | ((unsigned)f2bf(v.f[1]) << 16);
      o.y = (unsigned)f2bf(v.f[2]) | ((unsigned)f2bf(v.f[3]) << 16);
      o2[i] = o;
    }
    return;
  }

  int q = b - 27 - XB;
  const int *src, *dst;
  const float* w;
  int E, cap;
  int2* stg;
  int* bc;
  if (q < c1) {
    src = src1; dst = dst1; w = w1; E = E1; stg = stg1; bc = binCursor; cap = CAP1;
  } else {
    q -= c1;
    src = src2; dst = dst2; w = w2; E = E2; stg = stg2; bc = binCursor + NBINS; cap = CAP2;
  }
  int e0 = q * CHUNK;
  int n = E - e0;
  if (n > CHUNK) n = CHUNK;
  int t = threadIdx.x;

  for (int i = t; i < NBINS; i += 256) hist[i] = 0;
  __syncthreads();

  int2 pk[8];
#pragma unroll
  for (int j = 0; j < 8; j++) {
    int idx = t + j * 256;
    if (idx < n) {
      int d = dst[e0 + idx];
      int bin = d >> 7;
      pk[j] = make_int2(src[e0 + idx] | ((d & 127) << 16) | (bin << 23),
                        __float_as_int(w[e0 + idx]));
      atomicAdd(&hist[bin], 1);
    } else {
      pk[j].x = -1;
    }
  }
  __syncthreads();

  // exclusive scan hist -> sbase (thread t owns bins 2t, 2t+1; 196 active)
  int a0 = 0, a1 = 0;
  if (t < 196) {
    a0 = hist[2 * t];
    if (2 * t + 1 < NBINS) a1 = hist[2 * t + 1];
  }
  int s = a0 + a1;
  int lane = t & 63, wid = t >> 6;
  int ps = s;
#pragma unroll
  for (int off = 1; off < 64; off <<= 1) {
    int v = __shfl_up(ps, off, 64);
    if (lane >= off) ps += v;
  }
  if (lane == 63) wsum[wid] = ps;
  __syncthreads();
  if (t == 0) {
    int c = 0;
#pragma unroll
    for (int i = 0; i < 4; i++) { int tmp = wsum[i]; wsum[i] = c; c += tmp; }
  }
  __syncthreads();
  int excl = ps - s + wsum[wid];
  if (t < 196) {
    sbase[2 * t] = excl;
    cur[2 * t] = excl;
    if (2 * t + 1 < NBINS) { sbase[2 * t + 1] = excl + a0; cur[2 * t + 1] = excl + a0; }
  }
  __syncthreads();

#pragma unroll
  for (int j = 0; j < 8; j++) {
    if (pk[j].x != -1) {
      int bin = (pk[j].x >> 23) & 0x1FF;
      int pos = atomicAdd(&cur[bin], 1);
      buf[pos] = pk[j];
    }
  }
  for (int i = t; i < NBINS; i += 256) {
    int h = hist[i];
    segrel[i] = h ? atomicAdd(&bc[i], h) : 0;
  }
  __syncthreads();

  for (int i = t; i < n; i += 256) {
    int2 e = buf[i];
    int bin = (e.x >> 23) & 0x1FF;
    int pos = segrel[bin] + (i - sbase[bin]);
    if (pos < cap)
      stg[(size_t)bin * cap + pos] = make_int2(e.x & 0x7FFFFF, e.y);
  }
}

// ---------------------------------------------------------------------------
// binscan: exclusive scan of the NBINS bin counts per list (grid=2).
// ---------------------------------------------------------------------------
__global__ __launch_bounds__(512) void binscan(const int* __restrict__ cnt,
                                               int* __restrict__ scanout) {
  const int* in = cnt + blockIdx.x * NBINS;
  int* out = scanout + blockIdx.x * NBINS;
  int tid = threadIdx.x, lane = tid & 63, wid = tid >> 6;
  __shared__ int wsum[8];
  int v0 = (tid < NBINS) ? in[tid] : 0;
  int v = v0;
#pragma unroll
  for (int off = 1; off < 64; off <<= 1) {
    int t = __shfl_up(v, off, 64);
    if (lane >= off) v += t;
  }
  if (lane == 63) wsum[wid] = v;
  __syncthreads();
  if (tid < 8) {
    int s = wsum[tid], sc = s;
#pragma unroll
    for (int off = 1; off < 8; off <<= 1) {
      int t = __shfl_up(sc, off, 8);
      if (tid >= off) sc += t;
    }
    wsum[tid] = sc - s;
  }
  __syncthreads();
  if (tid < NBINS) out[tid] = v - v0 + wsum[wid];
}

// ---------------------------------------------------------------------------
// embed_place (fused, r9-proven): blocks [0,782) = embed MFMA from x_bf
// (PRE path: 1 A-load + 2 MFMA per nf) -> hcat[:,0:64] bf16;
// blocks [782, 782+2*NBINS) = per-bin CSR placement.
// C/D: col=lane&15, row=(lane>>4)*4+reg  [m89-verified]
// ---------------------------------------------------------------------------
__global__ __launch_bounds__(256) void embed_place(
    const u16* __restrict__ x_bf, const u16* __restrict__ wTh,
    const u16* __restrict__ wTl, const float* __restrict__ bias,
    u16* __restrict__ hcat, const int* __restrict__ binCursor,
    const int* __restrict__ binScan, const int2* __restrict__ stg1,
    int2* __restrict__ ew1, int* __restrict__ ep1,
    const int2* __restrict__ stg2, int2* __restrict__ ew2,
    int* __restrict__ ep2) {
  int b = blockIdx.x;
  if (b < 782) {
    int wave = threadIdx.x >> 6, lane = threadIdx.x & 63;
    int row0 = b * 64 + wave * 16;
    int m = lane & 15, kq = lane >> 4;
    int rowA = row0 + m;
    if (rowA >= N_NODES) rowA = N_NODES - 1;
    const u16* xr = x_bf + (size_t)rowA * IN_DIM;

    v4f acc[4];
#pragma unroll
    for (int nf = 0; nf < 4; nf++) acc[nf] = (v4f){0.f, 0.f, 0.f, 0.f};

#pragma unroll 4
    for (int k0 = 0; k0 < IN_DIM; k0 += 32) {
      int kk = k0 + kq * 8;
      v8s a = *(const v8s*)(xr + kk);
#pragma unroll
      for (int nf = 0; nf < 4; nf++) {
        int col = nf * 16 + m;
        v8s bh = *(const v8s*)(wTh + (size_t)col * IN_DIM + kk);
        v8s bl = *(const v8s*)(wTl + (size_t)col * IN_DIM + kk);
        acc[nf] = __builtin_amdgcn_mfma_f32_16x16x32_bf16(a, bh, acc[nf], 0, 0, 0);
        acc[nf] = __builtin_amdgcn_mfma_f32_16x16x32_bf16(a, bl, acc[nf], 0, 0, 0);
      }
    }

#pragma unroll
    for (int nf = 0; nf < 4; nf++) {
      int col = nf * 16 + m;
      float bv = bias[col];
#pragma unroll
      for (int reg = 0; reg < 4; reg++) {
        int rowC = row0 + kq * 4 + reg;
        if (rowC < N_NODES) {
          float v = acc[nf][reg] + bv;
          hcat[(size_t)rowC * HSTRIDE + col] = f2bf(v > 0.f ? v : 0.f);
        }
      }
    }
    return;
  }

  int pb = b - 782;
  int lb = pb < NBINS ? pb : pb - NBINS;
  const int2* stg;
  int2* ew;
  int* ep;
  int cap;
  if (pb < NBINS) { stg = stg1; ew = ew1; ep = ep1; cap = CAP1; }
  else            { stg = stg2; ew = ew2; ep = ep2; cap = CAP2; }
  int cnt = binCursor[pb];
  if (cnt > cap) cnt = cap;
  int base = binScan[pb];
  const int2* seg = stg + (size_t)lb * cap;
  int node0 = lb << 7;
  int nnodes = N_NODES - node0;
  if (nnodes > 128) nnodes = 128;

  __shared__ int ncnt[128], noff[128], ncur[128];
  __shared__ int t0;
  if (threadIdx.x < 128) { ncnt[threadIdx.x] = 0; ncur[threadIdx.x] = 0; }
  __syncthreads();
  for (int t = threadIdx.x; t < cnt; t += 256)
    atomicAdd(&ncnt[(seg[t].x >> 16) & 127], 1);
  __syncthreads();
  int v0 = 0, v = 0;
  if (threadIdx.x < 128) {
    v0 = ncnt[threadIdx.x];
    v = v0;
    int lane = threadIdx.x & 63;
#pragma unroll
    for (int off = 1; off < 64; off <<= 1) {
      int t = __shfl_up(v, off, 64);
      if (lane >= off) v += t;
    }
    if (threadIdx.x == 63) t0 = v;
  }
  __syncthreads();
  if (threadIdx.x < 128) {
    int excl = v - v0 + (threadIdx.x >= 64 ? t0 : 0);
    noff[threadIdx.x] = excl;
    if (threadIdx.x < nnodes) ep[node0 + threadIdx.x] = base + excl + v0;
  }
  __syncthreads();
  for (int t = threadIdx.x; t < cnt; t += 256) {
    int2 pk = seg[t];
    int nl = (pk.x >> 16) & 127;
    int pos = base + noff[nl] + atomicAdd(&ncur[nl], 1);
    ew[pos] = make_int2(pk.x & 0xFFFF, pk.y);
  }
}

// ---------------------------------------------------------------------------
// gather2 (fused pair): blocks [0,half) = list1 -> out1, rest = list2 -> out2.
// NT threads/node, each 8 bf16 cols (16B load/edge). fp32 acc, ReLU, bf16 out.
// ---------------------------------------------------------------------------
__device__ __forceinline__ void bf8_fma(const U4& r, float wt, float* a) {
#pragma unroll
  for (int i = 0; i < 4; i++) {
    a[2 * i]     += wt * __uint_as_float(r.u[i] << 16);
    a[2 * i + 1] += wt * __uint_as_float(r.u[i] & 0xffff0000u);
  }
}

template <int NT>
__global__ __launch_bounds__(256) void gather2(
    const int* __restrict__ ep1, const int2* __restrict__ ew1,
    const int* __restrict__ ep2, const int2* __restrict__ ew2,
    const u16* __restrict__ hin, u16* __restrict__ out1,
    u16* __restrict__ out2, int half_blocks) {
  int b = blockIdx.x;
  const int* ep;
  const int2* ew;
  u16* out;
  if (b < half_blocks) { ep = ep1; ew = ew1; out = out1; }
  else { b -= half_blocks; ep = ep2; ew = ew2; out = out2; }

  int tid = b * 256 + threadIdx.x;
  int node = tid / NT;
  if (node >= N_NODES) return;
  int col0 = (tid % NT) * 8;
  int s = node ? ep[node - 1] : 0;
  int e = ep[node];

  float a0[8], a1[8];
#pragma unroll
  for (int i = 0; i < 8; i++) { a0[i] = 0.f; a1[i] = 0.f; }

  int j = s;
  for (; j + 4 <= e; j += 4) {
    int2 p0 = ew[j], p1 = ew[j + 1], p2 = ew[j + 2], p3 = ew[j + 3];
    U4 r0, r1, r2, r3;
    r0.v = *(const uint4*)(hin + (size_t)p0.x * HSTRIDE + col0);
    r1.v = *(const uint4*)(hin + (size_t)p1.x * HSTRIDE + col0);
    r2.v = *(const uint4*)(hin + (size_t)p2.x * HSTRIDE + col0);
    r3.v = *(const uint4*)(hin + (size_t)p3.x * HSTRIDE + col0);
    bf8_fma(r0, __int_as_float(p0.y), a0);
    bf8_fma(r1, __int_as_float(p1.y), a1);
    bf8_fma(r2, __int_as_float(p2.y), a0);
    bf8_fma(r3, __int_as_float(p3.y), a1);
  }
  for (; j < e; j++) {
    int2 p = ew[j];
    U4 r;
    r.v = *(const uint4*)(hin + (size_t)p.x * HSTRIDE + col0);
    bf8_fma(r, __int_as_float(p.y), a0);
  }

  U4 o;
#pragma unroll
  for (int i = 0; i < 4; i++) {
    float lo = a0[2 * i] + a1[2 * i];
    float hi = a0[2 * i + 1] + a1[2 * i + 1];
    lo = lo > 0.f ? lo : 0.f;
    hi = hi > 0.f ? hi : 0.f;
    o.u[i] = ((unsigned)f2bf(hi) << 16) | (unsigned)f2bf(lo);
  }
  *(uint4*)(out + (size_t)node * HSTRIDE + col0) = o.v;
}

// ---------------------------------------------------------------------------
// final: out = hcat(bf16) @ cls_w + b. A direct bf16, B split hi/lo (2 MFMA).
// ---------------------------------------------------------------------------
__global__ __launch_bounds__(256) void final_mfma(
    const u16* __restrict__ hcat, const u16* __restrict__ wTh,
    const u16* __restrict__ wTl, const float* __restrict__ bias,
    float* __restrict__ out) {
  int wave = threadIdx.x >> 6, lane = threadIdx.x & 63;
  int row0 = blockIdx.x * 64 + wave * 16;
  int m = lane & 15, kq = lane >> 4;
  int rowA = row0 + m;
  if (rowA >= N_NODES) rowA = N_NODES - 1;
  const u16* hr = hcat + (size_t)rowA * HSTRIDE;

  v4f acc[3];
#pragma unroll
  for (int nf = 0; nf < 3; nf++) acc[nf] = (v4f){0.f, 0.f, 0.f, 0.f};

#pragma unroll 2
  for (int k0 = 0; k0 < HSTRIDE; k0 += 32) {
    int kk = k0 + kq * 8;
    v8s a = *(const v8s*)(hr + kk);
#pragma unroll
    for (int nf = 0; nf < 3; nf++) {
      int col = nf * 16 + m;
      v8s bh = *(const v8s*)(wTh + (size_t)col * HSTRIDE + kk);
      v8s bl = *(const v8s*)(wTl + (size_t)col * HSTRIDE + kk);
      acc[nf] = __builtin_amdgcn_mfma_f32_16x16x32_bf16(a, bh, acc[nf], 0, 0, 0);
      acc[nf] = __builtin_amdgcn_mfma_f32_16x16x32_bf16(a, bl, acc[nf], 0, 0, 0);
    }
  }

#pragma unroll
  for (int nf = 0; nf < 3; nf++) {
    int col = nf * 16 + m;
    if (col < OUT_DIM) {
      float bv = bias[col];
#pragma unroll
      for (int reg = 0; reg < 4; reg++) {
        int rowC = row0 + kq * 4 + reg;
        if (rowC < N_NODES)
          out[(size_t)rowC * OUT_DIM + col] = acc[nf][reg] + bv;
      }
    }
  }
}

// ---------------------------------------------------------------------------
extern "C" void kernel_launch(void* const* d_in, const int* in_sizes, int n_in,
                              void* d_out, int out_size, void* d_ws,
                              size_t ws_size, hipStream_t stream) {
  const float* x       = (const float*)d_in[0];
  const int*   src1    = (const int*)d_in[1];
  const int*   dst1    = (const int*)d_in[2];
  const float* w1      = (const float*)d_in[3];
  const int*   src2    = (const int*)d_in[4];
  const int*   dst2    = (const int*)d_in[5];
  const float* w2      = (const float*)d_in[6];
  const float* embed_w = (const float*)d_in[7];
  const float* embed_b = (const float*)d_in[8];
  const float* cls_w   = (const float*)d_in[9];
  const float* cls_b   = (const float*)d_in[10];
  int E1 = in_sizes[1];
  int E2 = in_sizes[4];

  float* ws = (float*)d_ws;
  size_t off = 0;
  u16* hcat = (u16*)(ws + off); off += (size_t)N_NODES * HSTRIDE / 2;
  int2* ew1 = (int2*)(ws + off); off += (size_t)2 * E1;
  int2* ew2 = (int2*)(ws + off); off += (size_t)2 * E2;
  int* ep1 = (int*)(ws + off); off += N_NODES;
  int* ep2 = (int*)(ws + off); off += N_NODES;
  int2* stg1 = (int2*)(ws + off); off += (size_t)2 * NBINS * CAP1;
  int2* stg2 = (int2*)(ws + off); off += (size_t)2 * NBINS * CAP2;
  int* binCursor = (int*)(ws + off); off += 2 * NBINS;
  int* binScan = (int*)(ws + off); off += 2 * NBINS;
  u16* weTh = (u16*)(ws + off); off += 16384;
  u16* weTl = (u16*)(ws + off); off += 16384;
  u16* wcTh = (u16*)(ws + off); off += 10752;
  u16* wcTl = (u16*)(ws + off); off += 10752;
  u16* x_bf = (u16*)(ws + off); off += (size_t)N_NODES * IN_DIM / 2;

  int c1 = (E1 + CHUNK - 1) / CHUNK;
  int c2 = (E2 + CHUNK - 1) / CHUNK;

  hipMemsetAsync(binCursor, 0, 2 * NBINS * sizeof(int), stream);
  prep<<<27 + XB + c1 + c2, 256, 0, stream>>>(
      embed_w, weTh, weTl, cls_w, wcTh, wcTl, x, x_bf,
      src1, dst1, w1, E1, c1, src2, dst2, w2, E2,
      binCursor, stg1, stg2);
  binscan<<<2, 512, 0, stream>>>(binCursor, binScan);
  embed_place<<<782 + 2 * NBINS, 256, 0, stream>>>(
      x_bf, weTh, weTl, embed_b, hcat, binCursor, binScan,
      stg1, ew1, ep1, stg2, ew2, ep2);
  // k=1: cols 64:128 <- A1 @ hcat[:,0:64]; cols 128:192 <- A2 @ same
  gather2<8><<<3126, 256, 0, stream>>>(ep1, ew1, ep2, ew2, hcat,
                                       hcat + 64, hcat + 128, 1563);
  // k=2: cols 192:320 <- A1 @ hcat[:,64:192]; cols 320:448 <- A2 @ same
  gather2<16><<<6250, 256, 0, stream>>>(ep1, ew1, ep2, ew2, hcat + 64,
                                        hcat + 192, hcat + 320, 3125);
  final_mfma<<<782, 256, 0, stream>>>(hcat, wcTh, wcTl, cls_b, (float*)d_out);
}

// Round 18
// 260.319 us; speedup vs baseline: 1.1328x; 1.0430x over previous
//
#include <hip/hip_runtime.h>

#define N_NODES 50000
#define IN_DIM 512
#define HIDDEN 64
#define OUT_DIM 47
#define HST 192      // hcat row stride (bf16): [h0(64) | hA(128)] — hB lives in LDS
#define KDIM 448     // final GEMM K (h0|hA|hB)

#define NBINS 391    // ceil(50000/128); bin = dst >> 7
#define CAP1 3072
#define CAP2 4096
#define CHUNK 2048   // edges per binning block (16 KB LDS sort buffer)
#define XB 1024      // x-conversion blocks

typedef unsigned short u16;
typedef short v8s __attribute__((ext_vector_type(8)));
typedef float v4f __attribute__((ext_vector_type(4)));

union F4 { float4 v; float f[4]; };
union U4 { uint4 v; unsigned u[4]; };

static __device__ __forceinline__ u16 f2bf(float f) {
  unsigned u = __float_as_uint(f);
  u += 0x7fffu + ((u >> 16) & 1u);
  return (u16)(u >> 16);
}
static __device__ __forceinline__ float bf2f(u16 h) {
  return __uint_as_float(((unsigned)h) << 16);
}

// ---------------------------------------------------------------------------
// prep (fused): [0,16) conv embed_w; [16,27) conv cls_w; [27,27+XB) x->bf16;
// [27+XB, ...) bin_edges LDS chunk-sort (burst staging writes).
// ---------------------------------------------------------------------------
__global__ __launch_bounds__(256) void prep(
    const float* __restrict__ embed_w, u16* __restrict__ weTh,
    u16* __restrict__ weTl, const float* __restrict__ cls_w,
    u16* __restrict__ wcTh, u16* __restrict__ wcTl,
    const float* __restrict__ x, u16* __restrict__ x_bf,
    const int* __restrict__ src1, const int* __restrict__ dst1,
    const float* __restrict__ w1, int E1, int c1,
    const int* __restrict__ src2, const int* __restrict__ dst2,
    const float* __restrict__ w2, int E2,
    int* __restrict__ binCursor, int2* __restrict__ stg1,
    int2* __restrict__ stg2) {
  __shared__ int hist[NBINS], sbase[NBINS], cur[NBINS], segrel[NBINS];
  __shared__ int wsum[4];
  __shared__ int2 buf[CHUNK];

  int b = blockIdx.x;
  if (b < 16) {
    int tid = b * 256 + threadIdx.x;  // 64 cols * 64 kgroups
    int col = tid >> 6;
    int k8 = (tid & 63) * 8;
#pragma unroll
    for (int j = 0; j < 8; j++) {
      float v = embed_w[(size_t)(k8 + j) * HIDDEN + col];
      u16 h = f2bf(v);
      weTh[(size_t)col * IN_DIM + k8 + j] = h;
      weTl[(size_t)col * IN_DIM + k8 + j] = f2bf(v - bf2f(h));
    }
    return;
  }
  if (b < 27) {
    int tid = (b - 16) * 256 + threadIdx.x;  // 48 cols * 56 kgroups
    if (tid < 48 * 56) {
      int col = tid / 56;
      int k8 = (tid % 56) * 8;
#pragma unroll
      for (int j = 0; j < 8; j++) {
        float v = (col < OUT_DIM) ? cls_w[(size_t)(k8 + j) * OUT_DIM + col] : 0.f;
        u16 h = f2bf(v);
        wcTh[(size_t)col * KDIM + k8 + j] = h;
        wcTl[(size_t)col * KDIM + k8 + j] = f2bf(v - bf2f(h));
      }
    }
    return;
  }
  if (b < 27 + XB) {
    const float4* x4 = (const float4*)x;
    uint2* o2 = (uint2*)x_bf;
    int i0 = (b - 27) * 256 + threadIdx.x;
    int stride = XB * 256;
    int tot = N_NODES * IN_DIM / 4;
    for (int i = i0; i < tot; i += stride) {
      F4 v;
      v.v = x4[i];
      uint2 o;
      o.x = (unsigned)f2bf(v.f[0]) | ((unsigned)f2bf(v.f[1]) << 16);
      o.y = (unsigned)f2bf(v.f[2]) | ((unsigned)f2bf(v.f[3]) << 16);
      o2[i] = o;
    }
    return;
  }

  int q = b - 27 - XB;
  const int *src, *dst;
  const float* w;
  int E, cap;
  int2* stg;
  int* bc;
  if (q < c1) {
    src = src1; dst = dst1; w = w1; E = E1; stg = stg1; bc = binCursor; cap = CAP1;
  } else {
    q -= c1;
    src = src2; dst = dst2; w = w2; E = E2; stg = stg2; bc = binCursor + NBINS; cap = CAP2;
  }
  int e0 = q * CHUNK;
  int n = E - e0;
  if (n > CHUNK) n = CHUNK;
  int t = threadIdx.x;

  for (int i = t; i < NBINS; i += 256) hist[i] = 0;
  __syncthreads();

  int2 pk[8];
#pragma unroll
  for (int j = 0; j < 8; j++) {
    int idx = t + j * 256;
    if (idx < n) {
      int d = dst[e0 + idx];
      int bin = d >> 7;
      pk[j] = make_int2(src[e0 + idx] | ((d & 127) << 16) | (bin << 23),
                        __float_as_int(w[e0 + idx]));
      atomicAdd(&hist[bin], 1);
    } else {
      pk[j].x = -1;
    }
  }
  __syncthreads();

  int a0 = 0, a1 = 0;
  if (t < 196) {
    a0 = hist[2 * t];
    if (2 * t + 1 < NBINS) a1 = hist[2 * t + 1];
  }
  int s = a0 + a1;
  int lane = t & 63, wid = t >> 6;
  int ps = s;
#pragma unroll
  for (int off = 1; off < 64; off <<= 1) {
    int v = __shfl_up(ps, off, 64);
    if (lane >= off) ps += v;
  }
  if (lane == 63) wsum[wid] = ps;
  __syncthreads();
  if (t == 0) {
    int c = 0;
#pragma unroll
    for (int i = 0; i < 4; i++) { int tmp = wsum[i]; wsum[i] = c; c += tmp; }
  }
  __syncthreads();
  int excl = ps - s + wsum[wid];
  if (t < 196) {
    sbase[2 * t] = excl;
    cur[2 * t] = excl;
    if (2 * t + 1 < NBINS) { sbase[2 * t + 1] = excl + a0; cur[2 * t + 1] = excl + a0; }
  }
  __syncthreads();

#pragma unroll
  for (int j = 0; j < 8; j++) {
    if (pk[j].x != -1) {
      int bin = (pk[j].x >> 23) & 0x1FF;
      int pos = atomicAdd(&cur[bin], 1);
      buf[pos] = pk[j];
    }
  }
  for (int i = t; i < NBINS; i += 256) {
    int h = hist[i];
    segrel[i] = h ? atomicAdd(&bc[i], h) : 0;
  }
  __syncthreads();

  for (int i = t; i < n; i += 256) {
    int2 e = buf[i];
    int bin = (e.x >> 23) & 0x1FF;
    int pos = segrel[bin] + (i - sbase[bin]);
    if (pos < cap)
      stg[(size_t)bin * cap + pos] = make_int2(e.x & 0x7FFFFF, e.y);
  }
}

// ---------------------------------------------------------------------------
// binscan: exclusive scan of the NBINS bin counts per list (grid=2).
// ---------------------------------------------------------------------------
__global__ __launch_bounds__(512) void binscan(const int* __restrict__ cnt,
                                               int* __restrict__ scanout) {
  const int* in = cnt + blockIdx.x * NBINS;
  int* out = scanout + blockIdx.x * NBINS;
  int tid = threadIdx.x, lane = tid & 63, wid = tid >> 6;
  __shared__ int wsum[8];
  int v0 = (tid < NBINS) ? in[tid] : 0;
  int v = v0;
#pragma unroll
  for (int off = 1; off < 64; off <<= 1) {
    int t = __shfl_up(v, off, 64);
    if (lane >= off) v += t;
  }
  if (lane == 63) wsum[wid] = v;
  __syncthreads();
  if (tid < 8) {
    int s = wsum[tid], sc = s;
#pragma unroll
    for (int off = 1; off < 8; off <<= 1) {
      int t = __shfl_up(sc, off, 8);
      if (tid >= off) sc += t;
    }
    wsum[tid] = sc - s;
  }
  __syncthreads();
  if (tid < NBINS) out[tid] = v - v0 + wsum[wid];
}

// ---------------------------------------------------------------------------
// embed_place (fused): blocks [0,782) = embed MFMA from x_bf -> hcat[:,0:64];
// blocks [782, 782+2*NBINS) = per-bin CSR placement.
// C/D: col=lane&15, row=(lane>>4)*4+reg  [m89-verified]
// ---------------------------------------------------------------------------
__global__ __launch_bounds__(256) void embed_place(
    const u16* __restrict__ x_bf, const u16* __restrict__ wTh,
    const u16* __restrict__ wTl, const float* __restrict__ bias,
    u16* __restrict__ hcat, const int* __restrict__ binCursor,
    const int* __restrict__ binScan, const int2* __restrict__ stg1,
    int2* __restrict__ ew1, int* __restrict__ ep1,
    const int2* __restrict__ stg2, int2* __restrict__ ew2,
    int* __restrict__ ep2) {
  int b = blockIdx.x;
  if (b < 782) {
    int wave = threadIdx.x >> 6, lane = threadIdx.x & 63;
    int row0 = b * 64 + wave * 16;
    int m = lane & 15, kq = lane >> 4;
    int rowA = row0 + m;
    if (rowA >= N_NODES) rowA = N_NODES - 1;
    const u16* xr = x_bf + (size_t)rowA * IN_DIM;

    v4f acc[4];
#pragma unroll
    for (int nf = 0; nf < 4; nf++) acc[nf] = (v4f){0.f, 0.f, 0.f, 0.f};

#pragma unroll 4
    for (int k0 = 0; k0 < IN_DIM; k0 += 32) {
      int kk = k0 + kq * 8;
      v8s a = *(const v8s*)(xr + kk);
#pragma unroll
      for (int nf = 0; nf < 4; nf++) {
        int col = nf * 16 + m;
        v8s bh = *(const v8s*)(wTh + (size_t)col * IN_DIM + kk);
        v8s bl = *(const v8s*)(wTl + (size_t)col * IN_DIM + kk);
        acc[nf] = __builtin_amdgcn_mfma_f32_16x16x32_bf16(a, bh, acc[nf], 0, 0, 0);
        acc[nf] = __builtin_amdgcn_mfma_f32_16x16x32_bf16(a, bl, acc[nf], 0, 0, 0);
      }
    }

#pragma unroll
    for (int nf = 0; nf < 4; nf++) {
      int col = nf * 16 + m;
      float bv = bias[col];
#pragma unroll
      for (int reg = 0; reg < 4; reg++) {
        int rowC = row0 + kq * 4 + reg;
        if (rowC < N_NODES) {
          float v = acc[nf][reg] + bv;
          hcat[(size_t)rowC * HST + col] = f2bf(v > 0.f ? v : 0.f);
        }
      }
    }
    return;
  }

  int pb = b - 782;
  int lb = pb < NBINS ? pb : pb - NBINS;
  const int2* stg;
  int2* ew;
  int* ep;
  int cap;
  if (pb < NBINS) { stg = stg1; ew = ew1; ep = ep1; cap = CAP1; }
  else            { stg = stg2; ew = ew2; ep = ep2; cap = CAP2; }
  int cnt = binCursor[pb];
  if (cnt > cap) cnt = cap;
  int base = binScan[pb];
  const int2* seg = stg + (size_t)lb * cap;
  int node0 = lb << 7;
  int nnodes = N_NODES - node0;
  if (nnodes > 128) nnodes = 128;

  __shared__ int ncnt[128], noff[128], ncur[128];
  __shared__ int t0;
  if (threadIdx.x < 128) { ncnt[threadIdx.x] = 0; ncur[threadIdx.x] = 0; }
  __syncthreads();
  for (int t = threadIdx.x; t < cnt; t += 256)
    atomicAdd(&ncnt[(seg[t].x >> 16) & 127], 1);
  __syncthreads();
  int v0 = 0, v = 0;
  if (threadIdx.x < 128) {
    v0 = ncnt[threadIdx.x];
    v = v0;
    int lane = threadIdx.x & 63;
#pragma unroll
    for (int off = 1; off < 64; off <<= 1) {
      int t = __shfl_up(v, off, 64);
      if (lane >= off) v += t;
    }
    if (threadIdx.x == 63) t0 = v;
  }
  __syncthreads();
  if (threadIdx.x < 128) {
    int excl = v - v0 + (threadIdx.x >= 64 ? t0 : 0);
    noff[threadIdx.x] = excl;
    if (threadIdx.x < nnodes) ep[node0 + threadIdx.x] = base + excl + v0;
  }
  __syncthreads();
  for (int t = threadIdx.x; t < cnt; t += 256) {
    int2 pk = seg[t];
    int nl = (pk.x >> 16) & 127;
    int pos = base + noff[nl] + atomicAdd(&ncur[nl], 1);
    ew[pos] = make_int2(pk.x & 0xFFFF, pk.y);
  }
}

// ---------------------------------------------------------------------------
// gather2 (k=1 fused pair): blocks [0,half) = list1 -> out1, rest = list2.
// NT threads/node, 8 bf16 cols each. fp32 acc, ReLU, bf16 out.
// ---------------------------------------------------------------------------
__device__ __forceinline__ void bf8_fma(const U4& r, float wt, float* a) {
#pragma unroll
  for (int i = 0; i < 4; i++) {
    a[2 * i]     += wt * __uint_as_float(r.u[i] << 16);
    a[2 * i + 1] += wt * __uint_as_float(r.u[i] & 0xffff0000u);
  }
}

template <int NT>
__global__ __launch_bounds__(256) void gather2(
    const int* __restrict__ ep1, const int2* __restrict__ ew1,
    const int* __restrict__ ep2, const int2* __restrict__ ew2,
    const u16* __restrict__ hin, u16* __restrict__ out1,
    u16* __restrict__ out2, int half_blocks) {
  int b = blockIdx.x;
  const int* ep;
  const int2* ew;
  u16* out;
  if (b < half_blocks) { ep = ep1; ew = ew1; out = out1; }
  else { b -= half_blocks; ep = ep2; ew = ew2; out = out2; }

  int tid = b * 256 + threadIdx.x;
  int node = tid / NT;
  if (node >= N_NODES) return;
  int col0 = (tid % NT) * 8;
  int s = node ? ep[node - 1] : 0;
  int e = ep[node];

  float a0[8], a1[8];
#pragma unroll
  for (int i = 0; i < 8; i++) { a0[i] = 0.f; a1[i] = 0.f; }

  int j = s;
  for (; j + 4 <= e; j += 4) {
    int2 p0 = ew[j], p1 = ew[j + 1], p2 = ew[j + 2], p3 = ew[j + 3];
    U4 r0, r1, r2, r3;
    r0.v = *(const uint4*)(hin + (size_t)p0.x * HST + col0);
    r1.v = *(const uint4*)(hin + (size_t)p1.x * HST + col0);
    r2.v = *(const uint4*)(hin + (size_t)p2.x * HST + col0);
    r3.v = *(const uint4*)(hin + (size_t)p3.x * HST + col0);
    bf8_fma(r0, __int_as_float(p0.y), a0);
    bf8_fma(r1, __int_as_float(p1.y), a1);
    bf8_fma(r2, __int_as_float(p2.y), a0);
    bf8_fma(r3, __int_as_float(p3.y), a1);
  }
  for (; j < e; j++) {
    int2 p = ew[j];
    U4 r;
    r.v = *(const uint4*)(hin + (size_t)p.x * HST + col0);
    bf8_fma(r, __int_as_float(p.y), a0);
  }

  U4 o;
#pragma unroll
  for (int i = 0; i < 4; i++) {
    float lo = a0[2 * i] + a1[2 * i];
    float hi = a0[2 * i + 1] + a1[2 * i + 1];
    lo = lo > 0.f ? lo : 0.f;
    hi = hi > 0.f ? hi : 0.f;
    o.u[i] = ((unsigned)f2bf(hi) << 16) | (unsigned)f2bf(lo);
  }
  *(uint4*)(out + (size_t)node * HST + col0) = o.v;
}

// ---------------------------------------------------------------------------
// gather16_final (fused k=2 gather + final GEMM): 3125 blocks x 16 nodes.
// Phase 1: each thread (nl=tid>>4, cg=(tid&15)*8) gathers list1 cols cg and
//   list2 cols cg of hA for node node0+nl -> ReLU -> bf16 LDS tile
//   hb[16][264] ([0:128)=list1, [128:256)=list2; 264-pitch => 2-way bank, free).
// Phase 2: waves 0-2 compute out[16 rows] = [h0|hA|hb] @ cls_w + b via MFMA
//   (A: K<192 from global hcat rows, K>=192 from LDS; C/D m89 layout).
// hB never touches global memory.
// ---------------------------------------------------------------------------
__global__ __launch_bounds__(256) void gather16_final(
    const int* __restrict__ ep1, const int2* __restrict__ ew1,
    const int* __restrict__ ep2, const int2* __restrict__ ew2,
    const u16* __restrict__ hcat, const u16* __restrict__ wTh,
    const u16* __restrict__ wTl, const float* __restrict__ bias,
    float* __restrict__ out) {
  __shared__ __align__(16) u16 hb[16][264];
  int node0 = blockIdx.x * 16;
  int tid = threadIdx.x;
  int nl = tid >> 4;
  int cg = (tid & 15) * 8;
  int node = node0 + nl;

#pragma unroll
  for (int list = 0; list < 2; list++) {
    const int* ep = list ? ep2 : ep1;
    const int2* ew = list ? ew2 : ew1;
    int s = node ? ep[node - 1] : 0;
    int e = ep[node];

    float a0[8], a1[8];
#pragma unroll
    for (int i = 0; i < 8; i++) { a0[i] = 0.f; a1[i] = 0.f; }

    int j = s;
    for (; j + 4 <= e; j += 4) {
      int2 p0 = ew[j], p1 = ew[j + 1], p2 = ew[j + 2], p3 = ew[j + 3];
      U4 r0, r1, r2, r3;
      r0.v = *(const uint4*)(hcat + (size_t)p0.x * HST + 64 + cg);
      r1.v = *(const uint4*)(hcat + (size_t)p1.x * HST + 64 + cg);
      r2.v = *(const uint4*)(hcat + (size_t)p2.x * HST + 64 + cg);
      r3.v = *(const uint4*)(hcat + (size_t)p3.x * HST + 64 + cg);
      bf8_fma(r0, __int_as_float(p0.y), a0);
      bf8_fma(r1, __int_as_float(p1.y), a1);
      bf8_fma(r2, __int_as_float(p2.y), a0);
      bf8_fma(r3, __int_as_float(p3.y), a1);
    }
    for (; j < e; j++) {
      int2 p = ew[j];
      U4 r;
      r.v = *(const uint4*)(hcat + (size_t)p.x * HST + 64 + cg);
      bf8_fma(r, __int_as_float(p.y), a0);
    }

    U4 o;
#pragma unroll
    for (int i = 0; i < 4; i++) {
      float lo = a0[2 * i] + a1[2 * i];
      float hi = a0[2 * i + 1] + a1[2 * i + 1];
      lo = lo > 0.f ? lo : 0.f;
      hi = hi > 0.f ? hi : 0.f;
      o.u[i] = ((unsigned)f2bf(hi) << 16) | (unsigned)f2bf(lo);
    }
    *(uint4*)(&hb[nl][list * 128 + cg]) = o.v;
  }
  __syncthreads();

  int wave = tid >> 6, lane = tid & 63;
  if (wave < 3) {
    int m = lane & 15, kq = lane >> 4;
    int col = wave * 16 + m;
    v4f acc = (v4f){0.f, 0.f, 0.f, 0.f};
    const u16* hr = hcat + (size_t)(node0 + m) * HST;

#pragma unroll
    for (int k0 = 0; k0 < KDIM; k0 += 32) {
      int kk = k0 + kq * 8;
      v8s a = (kk < 192) ? *(const v8s*)(hr + kk)
                         : *(const v8s*)(&hb[m][kk - 192]);
      v8s bh = *(const v8s*)(wTh + (size_t)col * KDIM + kk);
      v8s bl = *(const v8s*)(wTl + (size_t)col * KDIM + kk);
      acc = __builtin_amdgcn_mfma_f32_16x16x32_bf16(a, bh, acc, 0, 0, 0);
      acc = __builtin_amdgcn_mfma_f32_16x16x32_bf16(a, bl, acc, 0, 0, 0);
    }

    if (col < OUT_DIM) {
      float bv = bias[col];
#pragma unroll
      for (int reg = 0; reg < 4; reg++) {
        int row = node0 + kq * 4 + reg;
        out[(size_t)row * OUT_DIM + col] = acc[reg] + bv;
      }
    }
  }
}

// ---------------------------------------------------------------------------
extern "C" void kernel_launch(void* const* d_in, const int* in_sizes, int n_in,
                              void* d_out, int out_size, void* d_ws,
                              size_t ws_size, hipStream_t stream) {
  const float* x       = (const float*)d_in[0];
  const int*   src1    = (const int*)d_in[1];
  const int*   dst1    = (const int*)d_in[2];
  const float* w1      = (const float*)d_in[3];
  const int*   src2    = (const int*)d_in[4];
  const int*   dst2    = (const int*)d_in[5];
  const float* w2      = (const float*)d_in[6];
  const float* embed_w = (const float*)d_in[7];
  const float* embed_b = (const float*)d_in[8];
  const float* cls_w   = (const float*)d_in[9];
  const float* cls_b   = (const float*)d_in[10];
  int E1 = in_sizes[1];
  int E2 = in_sizes[4];

  float* ws = (float*)d_ws;
  size_t off = 0;
  u16* hcat = (u16*)(ws + off); off += (size_t)N_NODES * HST / 2;
  int2* ew1 = (int2*)(ws + off); off += (size_t)2 * E1;
  int2* ew2 = (int2*)(ws + off); off += (size_t)2 * E2;
  int* ep1 = (int*)(ws + off); off += N_NODES;
  int* ep2 = (int*)(ws + off); off += N_NODES;
  int2* stg1 = (int2*)(ws + off); off += (size_t)2 * NBINS * CAP1;
  int2* stg2 = (int2*)(ws + off); off += (size_t)2 * NBINS * CAP2;
  int* binCursor = (int*)(ws + off); off += 2 * NBINS;
  int* binScan = (int*)(ws + off); off += 2 * NBINS;
  u16* weTh = (u16*)(ws + off); off += 16384;
  u16* weTl = (u16*)(ws + off); off += 16384;
  u16* wcTh = (u16*)(ws + off); off += 10752;
  u16* wcTl = (u16*)(ws + off); off += 10752;
  u16* x_bf = (u16*)(ws + off); off += (size_t)N_NODES * IN_DIM / 2;

  int c1 = (E1 + CHUNK - 1) / CHUNK;
  int c2 = (E2 + CHUNK - 1) / CHUNK;

  hipMemsetAsync(binCursor, 0, 2 * NBINS * sizeof(int), stream);
  prep<<<27 + XB + c1 + c2, 256, 0, stream>>>(
      embed_w, weTh, weTl, cls_w, wcTh, wcTl, x, x_bf,
      src1, dst1, w1, E1, c1, src2, dst2, w2, E2,
      binCursor, stg1, stg2);
  binscan<<<2, 512, 0, stream>>>(binCursor, binScan);
  embed_place<<<782 + 2 * NBINS, 256, 0, stream>>>(
      x_bf, weTh, weTl, embed_b, hcat, binCursor, binScan,
      stg1, ew1, ep1, stg2, ew2, ep2);
  // k=1: cols 64:128 <- A1 @ hcat[:,0:64]; cols 128:192 <- A2 @ same
  gather2<8><<<3126, 256, 0, stream>>>(ep1, ew1, ep2, ew2, hcat,
                                       hcat + 64, hcat + 128, 1563);
  // k=2 + final fused: hB in LDS, out = [h0|hA|hB] @ cls_w + b
  gather16_final<<<3125, 256, 0, stream>>>(ep1, ew1, ep2, ew2, hcat,
                                           wcTh, wcTl, cls_b, (float*)d_out);
}

// Round 19
// 259.100 us; speedup vs baseline: 1.1381x; 1.0047x over previous
//
#include <hip/hip_runtime.h>

#define N_NODES 50000
#define IN_DIM 512
#define HIDDEN 64
#define OUT_DIM 47
#define HST 192      // hcat row stride (bf16): [h0(64) | hA(128)] — hB lives in LDS
#define KDIM 448     // final GEMM K (h0|hA|hB)

#define NBINS 391    // ceil(50000/128); bin = dst >> 7
#define CAP1 3072
#define CAP2 4096
#define CHUNK 2048   // edges per binning block (16 KB LDS sort buffer)
#define XB 1024      // x-conversion blocks

typedef unsigned short u16;
typedef short v8s __attribute__((ext_vector_type(8)));
typedef float v4f __attribute__((ext_vector_type(4)));

union F4 { float4 v; float f[4]; };
union U4 { uint4 v; unsigned u[4]; };

static __device__ __forceinline__ u16 f2bf(float f) {
  unsigned u = __float_as_uint(f);
  u += 0x7fffu + ((u >> 16) & 1u);
  return (u16)(u >> 16);
}
static __device__ __forceinline__ float bf2f(u16 h) {
  return __uint_as_float(((unsigned)h) << 16);
}

// ---------------------------------------------------------------------------
// prep (fused): [0,16) conv embed_w; [16,27) conv cls_w; [27,27+XB) x->bf16;
// [27+XB, ...) bin_edges LDS chunk-sort (burst staging writes).
// ---------------------------------------------------------------------------
__global__ __launch_bounds__(256) void prep(
    const float* __restrict__ embed_w, u16* __restrict__ weTh,
    u16* __restrict__ weTl, const float* __restrict__ cls_w,
    u16* __restrict__ wcTh, u16* __restrict__ wcTl,
    const float* __restrict__ x, u16* __restrict__ x_bf,
    const int* __restrict__ src1, const int* __restrict__ dst1,
    const float* __restrict__ w1, int E1, int c1,
    const int* __restrict__ src2, const int* __restrict__ dst2,
    const float* __restrict__ w2, int E2,
    int* __restrict__ binCursor, int2* __restrict__ stg1,
    int2* __restrict__ stg2) {
  __shared__ int hist[NBINS], sbase[NBINS], cur[NBINS], segrel[NBINS];
  __shared__ int wsum[4];
  __shared__ int2 buf[CHUNK];

  int b = blockIdx.x;
  if (b < 16) {
    int tid = b * 256 + threadIdx.x;  // 64 cols * 64 kgroups
    int col = tid >> 6;
    int k8 = (tid & 63) * 8;
#pragma unroll
    for (int j = 0; j < 8; j++) {
      float v = embed_w[(size_t)(k8 + j) * HIDDEN + col];
      u16 h = f2bf(v);
      weTh[(size_t)col * IN_DIM + k8 + j] = h;
      weTl[(size_t)col * IN_DIM + k8 + j] = f2bf(v - bf2f(h));
    }
    return;
  }
  if (b < 27) {
    int tid = (b - 16) * 256 + threadIdx.x;  // 48 cols * 56 kgroups
    if (tid < 48 * 56) {
      int col = tid / 56;
      int k8 = (tid % 56) * 8;
#pragma unroll
      for (int j = 0; j < 8; j++) {
        float v = (col < OUT_DIM) ? cls_w[(size_t)(k8 + j) * OUT_DIM + col] : 0.f;
        u16 h = f2bf(v);
        wcTh[(size_t)col * KDIM + k8 + j] = h;
        wcTl[(size_t)col * KDIM + k8 + j] = f2bf(v - bf2f(h));
      }
    }
    return;
  }
  if (b < 27 + XB) {
    const float4* x4 = (const float4*)x;
    uint2* o2 = (uint2*)x_bf;
    int i0 = (b - 27) * 256 + threadIdx.x;
    int stride = XB * 256;
    int tot = N_NODES * IN_DIM / 4;
    for (int i = i0; i < tot; i += stride) {
      F4 v;
      v.v = x4[i];
      uint2 o;
      o.x = (unsigned)f2bf(v.f[0]) | ((unsigned)f2bf(v.f[1]) << 16);
      o.y = (unsigned)f2bf(v.f[2]) | ((unsigned)f2bf(v.f[3]) << 16);
      o2[i] = o;
    }
    return;
  }

  int q = b - 27 - XB;
  const int *src, *dst;
  const float* w;
  int E, cap;
  int2* stg;
  int* bc;
  if (q < c1) {
    src = src1; dst = dst1; w = w1; E = E1; stg = stg1; bc = binCursor; cap = CAP1;
  } else {
    q -= c1;
    src = src2; dst = dst2; w = w2; E = E2; stg = stg2; bc = binCursor + NBINS; cap = CAP2;
  }
  int e0 = q * CHUNK;
  int n = E - e0;
  if (n > CHUNK) n = CHUNK;
  int t = threadIdx.x;

  for (int i = t; i < NBINS; i += 256) hist[i] = 0;
  __syncthreads();

  int2 pk[8];
#pragma unroll
  for (int j = 0; j < 8; j++) {
    int idx = t + j * 256;
    if (idx < n) {
      int d = dst[e0 + idx];
      int bin = d >> 7;
      pk[j] = make_int2(src[e0 + idx] | ((d & 127) << 16) | (bin << 23),
                        __float_as_int(w[e0 + idx]));
      atomicAdd(&hist[bin], 1);
    } else {
      pk[j].x = -1;
    }
  }
  __syncthreads();

  int a0 = 0, a1 = 0;
  if (t < 196) {
    a0 = hist[2 * t];
    if (2 * t + 1 < NBINS) a1 = hist[2 * t + 1];
  }
  int s = a0 + a1;
  int lane = t & 63, wid = t >> 6;
  int ps = s;
#pragma unroll
  for (int off = 1; off < 64; off <<= 1) {
    int v = __shfl_up(ps, off, 64);
    if (lane >= off) ps += v;
  }
  if (lane == 63) wsum[wid] = ps;
  __syncthreads();
  if (t == 0) {
    int c = 0;
#pragma unroll
    for (int i = 0; i < 4; i++) { int tmp = wsum[i]; wsum[i] = c; c += tmp; }
  }
  __syncthreads();
  int excl = ps - s + wsum[wid];
  if (t < 196) {
    sbase[2 * t] = excl;
    cur[2 * t] = excl;
    if (2 * t + 1 < NBINS) { sbase[2 * t + 1] = excl + a0; cur[2 * t + 1] = excl + a0; }
  }
  __syncthreads();

#pragma unroll
  for (int j = 0; j < 8; j++) {
    if (pk[j].x != -1) {
      int bin = (pk[j].x >> 23) & 0x1FF;
      int pos = atomicAdd(&cur[bin], 1);
      buf[pos] = pk[j];
    }
  }
  for (int i = t; i < NBINS; i += 256) {
    int h = hist[i];
    segrel[i] = h ? atomicAdd(&bc[i], h) : 0;
  }
  __syncthreads();

  for (int i = t; i < n; i += 256) {
    int2 e = buf[i];
    int bin = (e.x >> 23) & 0x1FF;
    int pos = segrel[bin] + (i - sbase[bin]);
    if (pos < cap)
      stg[(size_t)bin * cap + pos] = make_int2(e.x & 0x7FFFFF, e.y);
  }
}

// ---------------------------------------------------------------------------
// binscan: exclusive scan of the NBINS bin counts per list (grid=2).
// ---------------------------------------------------------------------------
__global__ __launch_bounds__(512) void binscan(const int* __restrict__ cnt,
                                               int* __restrict__ scanout) {
  const int* in = cnt + blockIdx.x * NBINS;
  int* out = scanout + blockIdx.x * NBINS;
  int tid = threadIdx.x, lane = tid & 63, wid = tid >> 6;
  __shared__ int wsum[8];
  int v0 = (tid < NBINS) ? in[tid] : 0;
  int v = v0;
#pragma unroll
  for (int off = 1; off < 64; off <<= 1) {
    int t = __shfl_up(v, off, 64);
    if (lane >= off) v += t;
  }
  if (lane == 63) wsum[wid] = v;
  __syncthreads();
  if (tid < 8) {
    int s = wsum[tid], sc = s;
#pragma unroll
    for (int off = 1; off < 8; off <<= 1) {
      int t = __shfl_up(sc, off, 8);
      if (tid >= off) sc += t;
    }
    wsum[tid] = sc - s;
  }
  __syncthreads();
  if (tid < NBINS) out[tid] = v - v0 + wsum[wid];
}

// ---------------------------------------------------------------------------
// embed_place (fused): blocks [0,782) = embed MFMA from x_bf -> hcat[:,0:64];
// blocks [782, 782+2*NBINS) = per-bin CSR placement.
// C/D: col=lane&15, row=(lane>>4)*4+reg  [m89-verified]
// ---------------------------------------------------------------------------
__global__ __launch_bounds__(256) void embed_place(
    const u16* __restrict__ x_bf, const u16* __restrict__ wTh,
    const u16* __restrict__ wTl, const float* __restrict__ bias,
    u16* __restrict__ hcat, const int* __restrict__ binCursor,
    const int* __restrict__ binScan, const int2* __restrict__ stg1,
    int2* __restrict__ ew1, int* __restrict__ ep1,
    const int2* __restrict__ stg2, int2* __restrict__ ew2,
    int* __restrict__ ep2) {
  int b = blockIdx.x;
  if (b < 782) {
    int wave = threadIdx.x >> 6, lane = threadIdx.x & 63;
    int row0 = b * 64 + wave * 16;
    int m = lane & 15, kq = lane >> 4;
    int rowA = row0 + m;
    if (rowA >= N_NODES) rowA = N_NODES - 1;
    const u16* xr = x_bf + (size_t)rowA * IN_DIM;

    v4f acc[4];
#pragma unroll
    for (int nf = 0; nf < 4; nf++) acc[nf] = (v4f){0.f, 0.f, 0.f, 0.f};

#pragma unroll 4
    for (int k0 = 0; k0 < IN_DIM; k0 += 32) {
      int kk = k0 + kq * 8;
      v8s a = *(const v8s*)(xr + kk);
#pragma unroll
      for (int nf = 0; nf < 4; nf++) {
        int col = nf * 16 + m;
        v8s bh = *(const v8s*)(wTh + (size_t)col * IN_DIM + kk);
        v8s bl = *(const v8s*)(wTl + (size_t)col * IN_DIM + kk);
        acc[nf] = __builtin_amdgcn_mfma_f32_16x16x32_bf16(a, bh, acc[nf], 0, 0, 0);
        acc[nf] = __builtin_amdgcn_mfma_f32_16x16x32_bf16(a, bl, acc[nf], 0, 0, 0);
      }
    }

#pragma unroll
    for (int nf = 0; nf < 4; nf++) {
      int col = nf * 16 + m;
      float bv = bias[col];
#pragma unroll
      for (int reg = 0; reg < 4; reg++) {
        int rowC = row0 + kq * 4 + reg;
        if (rowC < N_NODES) {
          float v = acc[nf][reg] + bv;
          hcat[(size_t)rowC * HST + col] = f2bf(v > 0.f ? v : 0.f);
        }
      }
    }
    return;
  }

  int pb = b - 782;
  int lb = pb < NBINS ? pb : pb - NBINS;
  const int2* stg;
  int2* ew;
  int* ep;
  int cap;
  if (pb < NBINS) { stg = stg1; ew = ew1; ep = ep1; cap = CAP1; }
  else            { stg = stg2; ew = ew2; ep = ep2; cap = CAP2; }
  int cnt = binCursor[pb];
  if (cnt > cap) cnt = cap;
  int base = binScan[pb];
  const int2* seg = stg + (size_t)lb * cap;
  int node0 = lb << 7;
  int nnodes = N_NODES - node0;
  if (nnodes > 128) nnodes = 128;

  __shared__ int ncnt[128], noff[128], ncur[128];
  __shared__ int t0;
  if (threadIdx.x < 128) { ncnt[threadIdx.x] = 0; ncur[threadIdx.x] = 0; }
  __syncthreads();
  for (int t = threadIdx.x; t < cnt; t += 256)
    atomicAdd(&ncnt[(seg[t].x >> 16) & 127], 1);
  __syncthreads();
  int v0 = 0, v = 0;
  if (threadIdx.x < 128) {
    v0 = ncnt[threadIdx.x];
    v = v0;
    int lane = threadIdx.x & 63;
#pragma unroll
    for (int off = 1; off < 64; off <<= 1) {
      int t = __shfl_up(v, off, 64);
      if (lane >= off) v += t;
    }
    if (threadIdx.x == 63) t0 = v;
  }
  __syncthreads();
  if (threadIdx.x < 128) {
    int excl = v - v0 + (threadIdx.x >= 64 ? t0 : 0);
    noff[threadIdx.x] = excl;
    if (threadIdx.x < nnodes) ep[node0 + threadIdx.x] = base + excl + v0;
  }
  __syncthreads();
  for (int t = threadIdx.x; t < cnt; t += 256) {
    int2 pk = seg[t];
    int nl = (pk.x >> 16) & 127;
    int pos = base + noff[nl] + atomicAdd(&ncur[nl], 1);
    ew[pos] = make_int2(pk.x & 0xFFFF, pk.y);
  }
}

// ---------------------------------------------------------------------------
// gather2 (k=1 fused pair): blocks [0,half) = list1 -> out1, rest = list2.
// NT threads/node, 8 bf16 cols each. fp32 acc, ReLU, bf16 out.
// ---------------------------------------------------------------------------
__device__ __forceinline__ void bf8_fma(const U4& r, float wt, float* a) {
#pragma unroll
  for (int i = 0; i < 4; i++) {
    a[2 * i]     += wt * __uint_as_float(r.u[i] << 16);
    a[2 * i + 1] += wt * __uint_as_float(r.u[i] & 0xffff0000u);
  }
}

template <int NT>
__global__ __launch_bounds__(256) void gather2(
    const int* __restrict__ ep1, const int2* __restrict__ ew1,
    const int* __restrict__ ep2, const int2* __restrict__ ew2,
    const u16* __restrict__ hin, u16* __restrict__ out1,
    u16* __restrict__ out2, int half_blocks) {
  int b = blockIdx.x;
  const int* ep;
  const int2* ew;
  u16* out;
  if (b < half_blocks) { ep = ep1; ew = ew1; out = out1; }
  else { b -= half_blocks; ep = ep2; ew = ew2; out = out2; }

  int tid = b * 256 + threadIdx.x;
  int node = tid / NT;
  if (node >= N_NODES) return;
  int col0 = (tid % NT) * 8;
  int s = node ? ep[node - 1] : 0;
  int e = ep[node];

  float a0[8], a1[8];
#pragma unroll
  for (int i = 0; i < 8; i++) { a0[i] = 0.f; a1[i] = 0.f; }

  int j = s;
  for (; j + 4 <= e; j += 4) {
    int2 p0 = ew[j], p1 = ew[j + 1], p2 = ew[j + 2], p3 = ew[j + 3];
    U4 r0, r1, r2, r3;
    r0.v = *(const uint4*)(hin + (size_t)p0.x * HST + col0);
    r1.v = *(const uint4*)(hin + (size_t)p1.x * HST + col0);
    r2.v = *(const uint4*)(hin + (size_t)p2.x * HST + col0);
    r3.v = *(const uint4*)(hin + (size_t)p3.x * HST + col0);
    bf8_fma(r0, __int_as_float(p0.y), a0);
    bf8_fma(r1, __int_as_float(p1.y), a1);
    bf8_fma(r2, __int_as_float(p2.y), a0);
    bf8_fma(r3, __int_as_float(p3.y), a1);
  }
  for (; j < e; j++) {
    int2 p = ew[j];
    U4 r;
    r.v = *(const uint4*)(hin + (size_t)p.x * HST + col0);
    bf8_fma(r, __int_as_float(p.y), a0);
  }

  U4 o;
#pragma unroll
  for (int i = 0; i < 4; i++) {
    float lo = a0[2 * i] + a1[2 * i];
    float hi = a0[2 * i + 1] + a1[2 * i + 1];
    lo = lo > 0.f ? lo : 0.f;
    hi = hi > 0.f ? hi : 0.f;
    o.u[i] = ((unsigned)f2bf(hi) << 16) | (unsigned)f2bf(lo);
  }
  *(uint4*)(out + (size_t)node * HST + col0) = o.v;
}

// ---------------------------------------------------------------------------
// gather16_final (fused k=2 gather + final GEMM): 3125 blocks x 512 threads,
// 16 nodes/block, 32 threads/node = (list, cg): the two edge lists' chains
// run CONCURRENTLY (r19: halves the per-node serial edge walk).
// Phase 1: thread (nl, list, cg) gathers its list's cols cg of hA -> ReLU ->
//   bf16 LDS hb[16][264] ([0:128)=list1, [128:256)=list2; 264-pitch).
// Phase 2: waves 0-2 compute out[16 rows] = [h0|hA|hb] @ cls_w + b via MFMA.
// hB never touches global memory.
// ---------------------------------------------------------------------------
__global__ __launch_bounds__(512) void gather16_final(
    const int* __restrict__ ep1, const int2* __restrict__ ew1,
    const int* __restrict__ ep2, const int2* __restrict__ ew2,
    const u16* __restrict__ hcat, const u16* __restrict__ wTh,
    const u16* __restrict__ wTl, const float* __restrict__ bias,
    float* __restrict__ out) {
  __shared__ __align__(16) u16 hb[16][264];
  int node0 = blockIdx.x * 16;
  int tid = threadIdx.x;
  int nl = tid >> 5;            // node 0..15
  int t5 = tid & 31;
  int list = t5 >> 4;           // 0 or 1
  int cg = (t5 & 15) * 8;       // col group 0..120
  int node = node0 + nl;

  {
    const int* ep = list ? ep2 : ep1;
    const int2* ew = list ? ew2 : ew1;
    int s = node ? ep[node - 1] : 0;
    int e = ep[node];

    float a0[8], a1[8];
#pragma unroll
    for (int i = 0; i < 8; i++) { a0[i] = 0.f; a1[i] = 0.f; }

    int j = s;
    for (; j + 4 <= e; j += 4) {
      int2 p0 = ew[j], p1 = ew[j + 1], p2 = ew[j + 2], p3 = ew[j + 3];
      U4 r0, r1, r2, r3;
      r0.v = *(const uint4*)(hcat + (size_t)p0.x * HST + 64 + cg);
      r1.v = *(const uint4*)(hcat + (size_t)p1.x * HST + 64 + cg);
      r2.v = *(const uint4*)(hcat + (size_t)p2.x * HST + 64 + cg);
      r3.v = *(const uint4*)(hcat + (size_t)p3.x * HST + 64 + cg);
      bf8_fma(r0, __int_as_float(p0.y), a0);
      bf8_fma(r1, __int_as_float(p1.y), a1);
      bf8_fma(r2, __int_as_float(p2.y), a0);
      bf8_fma(r3, __int_as_float(p3.y), a1);
    }
    for (; j < e; j++) {
      int2 p = ew[j];
      U4 r;
      r.v = *(const uint4*)(hcat + (size_t)p.x * HST + 64 + cg);
      bf8_fma(r, __int_as_float(p.y), a0);
    }

    U4 o;
#pragma unroll
    for (int i = 0; i < 4; i++) {
      float lo = a0[2 * i] + a1[2 * i];
      float hi = a0[2 * i + 1] + a1[2 * i + 1];
      lo = lo > 0.f ? lo : 0.f;
      hi = hi > 0.f ? hi : 0.f;
      o.u[i] = ((unsigned)f2bf(hi) << 16) | (unsigned)f2bf(lo);
    }
    *(uint4*)(&hb[nl][list * 128 + cg]) = o.v;
  }
  __syncthreads();

  int wave = tid >> 6, lane = tid & 63;
  if (wave < 3) {
    int m = lane & 15, kq = lane >> 4;
    int col = wave * 16 + m;
    v4f acc = (v4f){0.f, 0.f, 0.f, 0.f};
    const u16* hr = hcat + (size_t)(node0 + m) * HST;

#pragma unroll
    for (int k0 = 0; k0 < KDIM; k0 += 32) {
      int kk = k0 + kq * 8;
      v8s a = (kk < 192) ? *(const v8s*)(hr + kk)
                         : *(const v8s*)(&hb[m][kk - 192]);
      v8s bh = *(const v8s*)(wTh + (size_t)col * KDIM + kk);
      v8s bl = *(const v8s*)(wTl + (size_t)col * KDIM + kk);
      acc = __builtin_amdgcn_mfma_f32_16x16x32_bf16(a, bh, acc, 0, 0, 0);
      acc = __builtin_amdgcn_mfma_f32_16x16x32_bf16(a, bl, acc, 0, 0, 0);
    }

    if (col < OUT_DIM) {
      float bv = bias[col];
#pragma unroll
      for (int reg = 0; reg < 4; reg++) {
        int row = node0 + kq * 4 + reg;
        out[(size_t)row * OUT_DIM + col] = acc[reg] + bv;
      }
    }
  }
}

// ---------------------------------------------------------------------------
extern "C" void kernel_launch(void* const* d_in, const int* in_sizes, int n_in,
                              void* d_out, int out_size, void* d_ws,
                              size_t ws_size, hipStream_t stream) {
  const float* x       = (const float*)d_in[0];
  const int*   src1    = (const int*)d_in[1];
  const int*   dst1    = (const int*)d_in[2];
  const float* w1      = (const float*)d_in[3];
  const int*   src2    = (const int*)d_in[4];
  const int*   dst2    = (const int*)d_in[5];
  const float* w2      = (const float*)d_in[6];
  const float* embed_w = (const float*)d_in[7];
  const float* embed_b = (const float*)d_in[8];
  const float* cls_w   = (const float*)d_in[9];
  const float* cls_b   = (const float*)d_in[10];
  int E1 = in_sizes[1];
  int E2 = in_sizes[4];

  float* ws = (float*)d_ws;
  size_t off = 0;
  u16* hcat = (u16*)(ws + off); off += (size_t)N_NODES * HST / 2;
  int2* ew1 = (int2*)(ws + off); off += (size_t)2 * E1;
  int2* ew2 = (int2*)(ws + off); off += (size_t)2 * E2;
  int* ep1 = (int*)(ws + off); off += N_NODES;
  int* ep2 = (int*)(ws + off); off += N_NODES;
  int2* stg1 = (int2*)(ws + off); off += (size_t)2 * NBINS * CAP1;
  int2* stg2 = (int2*)(ws + off); off += (size_t)2 * NBINS * CAP2;
  int* binCursor = (int*)(ws + off); off += 2 * NBINS;
  int* binScan = (int*)(ws + off); off += 2 * NBINS;
  u16* weTh = (u16*)(ws + off); off += 16384;
  u16* weTl = (u16*)(ws + off); off += 16384;
  u16* wcTh = (u16*)(ws + off); off += 10752;
  u16* wcTl = (u16*)(ws + off); off += 10752;
  u16* x_bf = (u16*)(ws + off); off += (size_t)N_NODES * IN_DIM / 2;

  int c1 = (E1 + CHUNK - 1) / CHUNK;
  int c2 = (E2 + CHUNK - 1) / CHUNK;

  hipMemsetAsync(binCursor, 0, 2 * NBINS * sizeof(int), stream);
  prep<<<27 + XB + c1 + c2, 256, 0, stream>>>(
      embed_w, weTh, weTl, cls_w, wcTh, wcTl, x, x_bf,
      src1, dst1, w1, E1, c1, src2, dst2, w2, E2,
      binCursor, stg1, stg2);
  binscan<<<2, 512, 0, stream>>>(binCursor, binScan);
  embed_place<<<782 + 2 * NBINS, 256, 0, stream>>>(
      x_bf, weTh, weTl, embed_b, hcat, binCursor, binScan,
      stg1, ew1, ep1, stg2, ew2, ep2);
  // k=1: cols 64:128 <- A1 @ hcat[:,0:64]; cols 128:192 <- A2 @ same
  gather2<8><<<3126, 256, 0, stream>>>(ep1, ew1, ep2, ew2, hcat,
                                       hcat + 64, hcat + 128, 1563);
  // k=2 + final fused: hB in LDS, out = [h0|hA|hB] @ cls_w + b
  gather16_final<<<3125, 512, 0, stream>>>(ep1, ew1, ep2, ew2, hcat,
                                           wcTh, wcTl, cls_b, (float*)d_out);
}